// Round 1
// baseline (1071.124 us; speedup 1.0000x reference)
//
#include <hip/hip_runtime.h>
#include <hip/hip_bf16.h>

#define N_NODES 100000
#define LRELU_SLOPE 0.2f

__device__ __forceinline__ void atomAddF(float* p, float v) {
    unsafeAtomicAdd(p, v);   // native global_atomic_add_f32 on gfx950
}

__device__ __forceinline__ float lrelu(float a) {
    return a > 0.f ? a : LRELU_SLOPE * a;
}

// ---------------- GEMM: X[nrows,K] @ W[K,64] -> OUT[nrows,64], f32 ----------------
template<int K>
__global__ __launch_bounds__(256) void gemm_rowtile(
    const float* __restrict__ X, const float* __restrict__ W,
    float* __restrict__ OUT, int nrows)
{
    __shared__ float xs[64][33];   // row-major, +1 pad
    __shared__ float ws[32][64];   // k-major
    const int tid = threadIdx.x;
    const int block_row = blockIdx.x * 64;
    const int tx = tid & 15, ty = tid >> 4;   // 16x16 thread grid, 4x4 outputs each
    float acc[4][4] = {};

    for (int k0 = 0; k0 < K; k0 += 32) {
        // stage X tile 64x32 (2 float4 per thread)
        #pragma unroll
        for (int half = 0; half < 2; ++half) {
            int r = (tid >> 3) + 32 * half;
            int kq = (tid & 7) * 4;
            int gr = block_row + r;
            float4 v = make_float4(0.f, 0.f, 0.f, 0.f);
            if (gr < nrows) v = *(const float4*)(X + (size_t)gr * K + k0 + kq);
            xs[r][kq + 0] = v.x; xs[r][kq + 1] = v.y;
            xs[r][kq + 2] = v.z; xs[r][kq + 3] = v.w;
        }
        // stage W tile 32x64 (2 float4 per thread, linear)
        #pragma unroll
        for (int half = 0; half < 2; ++half) {
            int i = tid + 256 * half;
            int r = i >> 4, cq = (i & 15) << 2;
            float4 w = *(const float4*)(W + (size_t)(k0 + r) * 64 + cq);
            *(float4*)&ws[r][cq] = w;
        }
        __syncthreads();
        #pragma unroll
        for (int kk = 0; kk < 32; ++kk) {
            float4 wv = *(const float4*)&ws[kk][tx << 2];
            float xr[4];
            #pragma unroll
            for (int i = 0; i < 4; ++i) xr[i] = xs[(ty << 2) + i][kk];
            #pragma unroll
            for (int i = 0; i < 4; ++i) {
                acc[i][0] += xr[i] * wv.x; acc[i][1] += xr[i] * wv.y;
                acc[i][2] += xr[i] * wv.z; acc[i][3] += xr[i] * wv.w;
            }
        }
        __syncthreads();
    }
    #pragma unroll
    for (int i = 0; i < 4; ++i) {
        int gr = block_row + (ty << 2) + i;
        if (gr < nrows) {
            float4 o = make_float4(acc[i][0], acc[i][1], acc[i][2], acc[i][3]);
            *(float4*)(OUT + (size_t)gr * 64 + (tx << 2)) = o;
        }
    }
}

// ---------------- per-node attention logits, 8 heads x 8 ch ----------------
__global__ __launch_bounds__(256) void node_att_h8(
    const float* __restrict__ H, const float* __restrict__ att_s,
    const float* __restrict__ att_d,
    float* __restrict__ a_src, float* __restrict__ a_dst, int n)
{
    int node = blockIdx.x * 4 + (threadIdx.x >> 6);
    if (node >= n) return;
    int lane = threadIdx.x & 63;
    float h = H[(size_t)node * 64 + lane];
    float ps = h * att_s[lane];
    float pd = h * att_d[lane];
    #pragma unroll
    for (int off = 1; off < 8; off <<= 1) {
        ps += __shfl_xor(ps, off, 64);
        pd += __shfl_xor(pd, off, 64);
    }
    if ((lane & 7) == 0) {
        a_src[(size_t)node * 8 + (lane >> 3)] = ps;
        a_dst[(size_t)node * 8 + (lane >> 3)] = pd;
    }
}

// ---------------- per-node attention logits, 1 head x 64 ch ----------------
__global__ __launch_bounds__(256) void node_att_h1(
    const float* __restrict__ H, const float* __restrict__ att_s,
    const float* __restrict__ att_d,
    float* __restrict__ a_src, float* __restrict__ a_dst, int n)
{
    int node = blockIdx.x * 4 + (threadIdx.x >> 6);
    if (node >= n) return;
    int lane = threadIdx.x & 63;
    float h = H[(size_t)node * 64 + lane];
    float ps = h * att_s[lane];
    float pd = h * att_d[lane];
    #pragma unroll
    for (int off = 1; off < 64; off <<= 1) {
        ps += __shfl_xor(ps, off, 64);
        pd += __shfl_xor(pd, off, 64);
    }
    if (lane == 0) { a_src[node] = ps; a_dst[node] = pd; }
}

// ---------------- edge denom, 8 heads: thread per (edge, head) ----------------
__global__ __launch_bounds__(256) void edge_denom_h8(
    const int* __restrict__ ei, int E_, int ET,
    const float* __restrict__ a_src, const float* __restrict__ a_dst,
    float* __restrict__ denom)
{
    int t = blockIdx.x * 256 + threadIdx.x;
    if (t >= ET * 8) return;
    int e = t >> 3, h = t & 7;
    int s, d;
    if (e < E_) { s = ei[e]; d = ei[E_ + e]; } else { s = d = e - E_; }
    float a = lrelu(a_src[(size_t)s * 8 + h] + a_dst[(size_t)d * 8 + h]);
    atomAddF(&denom[(size_t)d * 8 + h], __expf(a));
}

// ---------------- edge denom, 1 head: thread per edge ----------------
__global__ __launch_bounds__(256) void edge_denom_h1(
    const int* __restrict__ ei, int E_, int ET,
    const float* __restrict__ a_src, const float* __restrict__ a_dst,
    float* __restrict__ denom)
{
    int e = blockIdx.x * 256 + threadIdx.x;
    if (e >= ET) return;
    int s, d;
    if (e < E_) { s = ei[e]; d = ei[E_ + e]; } else { s = d = e - E_; }
    float a = lrelu(a_src[s] + a_dst[d]);
    atomAddF(&denom[d], __expf(a));
}

// ---------------- edge scatter, 8 heads: wave per edge, lane = h*8+c ----------------
__global__ __launch_bounds__(256) void edge_scatter_h8(
    const int* __restrict__ ei, int E_, int ET,
    const float* __restrict__ a_src, const float* __restrict__ a_dst,
    const float* __restrict__ denom,
    const float* __restrict__ H, float* __restrict__ OUT)
{
    int e = blockIdx.x * 4 + (threadIdx.x >> 6);
    if (e >= ET) return;
    int lane = threadIdx.x & 63;
    int h = lane >> 3;
    int s, d;
    if (e < E_) { s = ei[e]; d = ei[E_ + e]; } else { s = d = e - E_; }
    float a = lrelu(a_src[(size_t)s * 8 + h] + a_dst[(size_t)d * 8 + h]);
    float coef = __expf(a) / (denom[(size_t)d * 8 + h] + 1e-16f);
    float hv = H[(size_t)s * 64 + lane];
    atomAddF(&OUT[(size_t)d * 64 + lane], coef * hv);
}

// ---------------- edge scatter, 1 head: wave per edge ----------------
__global__ __launch_bounds__(256) void edge_scatter_h1(
    const int* __restrict__ ei, int E_, int ET,
    const float* __restrict__ a_src, const float* __restrict__ a_dst,
    const float* __restrict__ denom,
    const float* __restrict__ H, float* __restrict__ OUT)
{
    int e = blockIdx.x * 4 + (threadIdx.x >> 6);
    if (e >= ET) return;
    int lane = threadIdx.x & 63;
    int s, d;
    if (e < E_) { s = ei[e]; d = ei[E_ + e]; } else { s = d = e - E_; }
    float a = lrelu(a_src[s] + a_dst[d]);
    float coef = __expf(a) / (denom[d] + 1e-16f);
    float hv = H[(size_t)s * 64 + lane];
    atomAddF(&OUT[(size_t)d * 64 + lane], coef * hv);
}

// ---------------- bias + ELU in place ----------------
__global__ __launch_bounds__(256) void bias_elu(
    float* __restrict__ X, const float* __restrict__ b, int n64)
{
    int i = blockIdx.x * 256 + threadIdx.x;
    if (i >= n64) return;
    float v = X[i] + b[i & 63];
    X[i] = v > 0.f ? v : expm1f(v);
}

// ---------------- bias + log_softmax (wave per node) ----------------
__global__ __launch_bounds__(256) void bias_logsoftmax(
    const float* __restrict__ ACC, const float* __restrict__ b,
    float* __restrict__ OUT, int n)
{
    int node = blockIdx.x * 4 + (threadIdx.x >> 6);
    if (node >= n) return;
    int lane = threadIdx.x & 63;
    float v = ACC[(size_t)node * 64 + lane] + b[lane];
    float m = v;
    #pragma unroll
    for (int off = 1; off < 64; off <<= 1) m = fmaxf(m, __shfl_xor(m, off));
    float ex = __expf(v - m);
    float sum = ex;
    #pragma unroll
    for (int off = 1; off < 64; off <<= 1) sum += __shfl_xor(sum, off);
    OUT[(size_t)node * 64 + lane] = v - m - __logf(sum);
}

extern "C" void kernel_launch(void* const* d_in, const int* in_sizes, int n_in,
                              void* d_out, int out_size, void* d_ws, size_t ws_size,
                              hipStream_t stream)
{
    const float* x    = (const float*)d_in[0];
    const int*   ei   = (const int*)d_in[1];
    const float* W1   = (const float*)d_in[2];
    const float* as1w = (const float*)d_in[3];
    const float* ad1w = (const float*)d_in[4];
    const float* b1   = (const float*)d_in[5];
    const float* W2   = (const float*)d_in[6];
    const float* as2w = (const float*)d_in[7];
    const float* ad2w = (const float*)d_in[8];
    const float* b2   = (const float*)d_in[9];
    float* out = (float*)d_out;

    const int n  = in_sizes[0] / 256;     // 100000
    const int E_ = in_sizes[1] / 2;       // 1600000
    const int ET = E_ + n;                // + self loops

    float* ws   = (float*)d_ws;
    float* A    = ws;                         // h1, later h2      [n*64]
    float* B    = A + (size_t)n * 64;         // acc1/hact, acc2   [n*64]
    float* a_s1 = B + (size_t)n * 64;         // [n*8]
    float* a_d1 = a_s1 + (size_t)n * 8;       // [n*8]
    float* dn1  = a_d1 + (size_t)n * 8;       // [n*8]
    float* a_s2 = dn1 + (size_t)n * 8;        // [n]
    float* a_d2 = a_s2 + n;                   // [n]
    float* dn2  = a_d2 + n;                   // [n]

    const int gemm_grid = (n + 63) / 64;

    // ---- layer 1 ----
    hipMemsetAsync(dn1, 0, (size_t)n * 8 * sizeof(float), stream);
    hipMemsetAsync(B, 0, (size_t)n * 64 * sizeof(float), stream);
    gemm_rowtile<256><<<gemm_grid, 256, 0, stream>>>(x, W1, A, n);
    node_att_h8<<<(n + 3) / 4, 256, 0, stream>>>(A, as1w, ad1w, a_s1, a_d1, n);
    edge_denom_h8<<<(ET * 8 + 255) / 256, 256, 0, stream>>>(ei, E_, ET, a_s1, a_d1, dn1);
    edge_scatter_h8<<<(ET + 3) / 4, 256, 0, stream>>>(ei, E_, ET, a_s1, a_d1, dn1, A, B);
    bias_elu<<<(n * 64 + 255) / 256, 256, 0, stream>>>(B, b1, n * 64);

    // ---- layer 2 ----
    gemm_rowtile<64><<<gemm_grid, 256, 0, stream>>>(B, W2, A, n);
    node_att_h1<<<(n + 3) / 4, 256, 0, stream>>>(A, as2w, ad2w, a_s2, a_d2, n);
    hipMemsetAsync(dn2, 0, (size_t)n * sizeof(float), stream);
    edge_denom_h1<<<(ET + 255) / 256, 256, 0, stream>>>(ei, E_, ET, a_s2, a_d2, dn2);
    hipMemsetAsync(B, 0, (size_t)n * 64 * sizeof(float), stream);
    edge_scatter_h1<<<(ET + 3) / 4, 256, 0, stream>>>(ei, E_, ET, a_s2, a_d2, dn2, A, B);
    bias_logsoftmax<<<(n + 3) / 4, 256, 0, stream>>>(B, b2, out, n);
}

// Round 2
// 668.556 us; speedup vs baseline: 1.6021x; 1.6021x over previous
//
#include <hip/hip_runtime.h>
#include <hip/hip_bf16.h>

#define LRELU_SLOPE 0.2f

typedef unsigned int uint;
typedef unsigned short ushort;

__device__ __forceinline__ void atomAddF(float* p, float v) {
    unsafeAtomicAdd(p, v);   // native global_atomic_add_f32 on gfx950
}

// packed bf16x2 atomic add (native on gfx950)
__device__ __forceinline__ void atomAddBf16x2(void* p, uint v) {
    asm volatile("global_atomic_pk_add_bf16 %0, %1, off" :: "v"(p), "v"(v) : "memory");
}

__device__ __forceinline__ float lrelu(float a) {
    return a > 0.f ? a : LRELU_SLOPE * a;
}

__device__ __forceinline__ ushort f2bf(float f) {   // RNE, NaN-unsafe (fine here)
    uint u = __float_as_uint(f);
    return (ushort)((u + 0x7FFF + ((u >> 16) & 1)) >> 16);
}
__device__ __forceinline__ float bf2f(ushort h) {
    return __uint_as_float(((uint)h) << 16);
}

// ---------------- GEMM: X[nrows,K] @ W[K,64] -> OUT[nrows,64] in bf16 ----------------
template<int K>
__global__ __launch_bounds__(256) void gemm_bf16out(
    const float* __restrict__ X, const float* __restrict__ W,
    ushort* __restrict__ OUT, int nrows)
{
    __shared__ float xs[64][33];
    __shared__ float ws[32][64];
    const int tid = threadIdx.x;
    const int block_row = blockIdx.x * 64;
    const int tx = tid & 15, ty = tid >> 4;
    float acc[4][4] = {};

    for (int k0 = 0; k0 < K; k0 += 32) {
        #pragma unroll
        for (int half = 0; half < 2; ++half) {
            int r = (tid >> 3) + 32 * half;
            int kq = (tid & 7) * 4;
            int gr = block_row + r;
            float4 v = make_float4(0.f, 0.f, 0.f, 0.f);
            if (gr < nrows) v = *(const float4*)(X + (size_t)gr * K + k0 + kq);
            xs[r][kq + 0] = v.x; xs[r][kq + 1] = v.y;
            xs[r][kq + 2] = v.z; xs[r][kq + 3] = v.w;
        }
        #pragma unroll
        for (int half = 0; half < 2; ++half) {
            int i = tid + 256 * half;
            int r = i >> 4, cq = (i & 15) << 2;
            float4 w = *(const float4*)(W + (size_t)(k0 + r) * 64 + cq);
            *(float4*)&ws[r][cq] = w;
        }
        __syncthreads();
        #pragma unroll
        for (int kk = 0; kk < 32; ++kk) {
            float4 wv = *(const float4*)&ws[kk][tx << 2];
            float xr[4];
            #pragma unroll
            for (int i = 0; i < 4; ++i) xr[i] = xs[(ty << 2) + i][kk];
            #pragma unroll
            for (int i = 0; i < 4; ++i) {
                acc[i][0] += xr[i] * wv.x; acc[i][1] += xr[i] * wv.y;
                acc[i][2] += xr[i] * wv.z; acc[i][3] += xr[i] * wv.w;
            }
        }
        __syncthreads();
    }
    #pragma unroll
    for (int i = 0; i < 4; ++i) {
        int gr = block_row + (ty << 2) + i;
        if (gr < nrows) {
            uint2 o;
            o.x = (uint)f2bf(acc[i][0]) | ((uint)f2bf(acc[i][1]) << 16);
            o.y = (uint)f2bf(acc[i][2]) | ((uint)f2bf(acc[i][3]) << 16);
            *(uint2*)(OUT + (size_t)gr * 64 + (tx << 2)) = o;
        }
    }
}

// ---------------- per-node attention logits, 8 heads x 8 ch (bf16 in) ----------------
__global__ __launch_bounds__(256) void node_att_h8(
    const ushort* __restrict__ H, const float* __restrict__ att_s,
    const float* __restrict__ att_d,
    float* __restrict__ a_src, float* __restrict__ a_dst, int n)
{
    int node = blockIdx.x * 4 + (threadIdx.x >> 6);
    if (node >= n) return;
    int lane = threadIdx.x & 63;
    float h = bf2f(H[(size_t)node * 64 + lane]);
    float ps = h * att_s[lane];
    float pd = h * att_d[lane];
    #pragma unroll
    for (int off = 1; off < 8; off <<= 1) {
        ps += __shfl_xor(ps, off, 64);
        pd += __shfl_xor(pd, off, 64);
    }
    if ((lane & 7) == 0) {
        a_src[(size_t)node * 8 + (lane >> 3)] = ps;
        a_dst[(size_t)node * 8 + (lane >> 3)] = pd;
    }
}

// ---------------- per-node attention logits, 1 head x 64 ch (bf16 in) ----------------
__global__ __launch_bounds__(256) void node_att_h1(
    const ushort* __restrict__ H, const float* __restrict__ att_s,
    const float* __restrict__ att_d,
    float* __restrict__ a_src, float* __restrict__ a_dst, int n)
{
    int node = blockIdx.x * 4 + (threadIdx.x >> 6);
    if (node >= n) return;
    int lane = threadIdx.x & 63;
    float h = bf2f(H[(size_t)node * 64 + lane]);
    float ps = h * att_s[lane];
    float pd = h * att_d[lane];
    #pragma unroll
    for (int off = 1; off < 64; off <<= 1) {
        ps += __shfl_xor(ps, off, 64);
        pd += __shfl_xor(pd, off, 64);
    }
    if (lane == 0) { a_src[node] = ps; a_dst[node] = pd; }
}

// ---- fused edge pass, 8 heads: half-wave per edge, unnormalized accumulate ----
__global__ __launch_bounds__(256) void edge_fused_h8(
    const int* __restrict__ ei, int E_, int ET,
    const float* __restrict__ a_src, const float* __restrict__ a_dst,
    float* __restrict__ denom,
    const ushort* __restrict__ HB, ushort* __restrict__ ACC)
{
    int e = blockIdx.x * 8 + (threadIdx.x >> 5);   // 8 half-waves per block
    if (e >= ET) return;
    int c2 = threadIdx.x & 31;                     // channel pair 0..31
    int s, d;
    if (e < E_) { s = ei[e]; d = ei[E_ + e]; } else { s = d = e - E_; }
    int head = c2 >> 2;
    float a = lrelu(a_src[(size_t)s * 8 + head] + a_dst[(size_t)d * 8 + head]);
    float ex = __expf(a);
    if ((c2 & 3) == 0) atomAddF(&denom[(size_t)d * 8 + head], ex);
    uint hv = *(const uint*)(HB + (size_t)s * 64 + c2 * 2);
    float v0 = ex * bf2f((ushort)(hv & 0xffff));
    float v1 = ex * bf2f((ushort)(hv >> 16));
    uint pv = (uint)f2bf(v0) | ((uint)f2bf(v1) << 16);
    atomAddBf16x2(ACC + (size_t)d * 64 + c2 * 2, pv);
}

// ---- fused edge pass, 1 head: half-wave per edge ----
__global__ __launch_bounds__(256) void edge_fused_h1(
    const int* __restrict__ ei, int E_, int ET,
    const float* __restrict__ a_src, const float* __restrict__ a_dst,
    float* __restrict__ denom,
    const ushort* __restrict__ HB, ushort* __restrict__ ACC)
{
    int e = blockIdx.x * 8 + (threadIdx.x >> 5);
    if (e >= ET) return;
    int c2 = threadIdx.x & 31;
    int s, d;
    if (e < E_) { s = ei[e]; d = ei[E_ + e]; } else { s = d = e - E_; }
    float a = lrelu(a_src[s] + a_dst[d]);
    float ex = __expf(a);
    if (c2 == 0) atomAddF(&denom[d], ex);
    uint hv = *(const uint*)(HB + (size_t)s * 64 + c2 * 2);
    float v0 = ex * bf2f((ushort)(hv & 0xffff));
    float v1 = ex * bf2f((ushort)(hv >> 16));
    uint pv = (uint)f2bf(v0) | ((uint)f2bf(v1) << 16);
    atomAddBf16x2(ACC + (size_t)d * 64 + c2 * 2, pv);
}

// ---------------- normalize + bias + ELU: ACC(bf16)/denom -> B(f32) ----------------
__global__ __launch_bounds__(256) void norm_bias_elu(
    const ushort* __restrict__ ACC, const float* __restrict__ denom,
    const float* __restrict__ b, float* __restrict__ B, int n)
{
    int i = blockIdx.x * 256 + threadIdx.x;       // pair index, n*32 total
    if (i >= n * 32) return;
    int node = i >> 5, p = i & 31;
    float dn = denom[(size_t)node * 8 + (p >> 2)] + 1e-16f;
    uint hv = *(const uint*)(ACC + (size_t)i * 2);
    float v0 = bf2f((ushort)(hv & 0xffff)) / dn + b[p * 2];
    float v1 = bf2f((ushort)(hv >> 16))    / dn + b[p * 2 + 1];
    v0 = v0 > 0.f ? v0 : expm1f(v0);
    v1 = v1 > 0.f ? v1 : expm1f(v1);
    *(float2*)(B + (size_t)i * 2) = make_float2(v0, v1);
}

// ---------------- normalize + bias + log_softmax (wave per node) ----------------
__global__ __launch_bounds__(256) void norm_bias_logsoftmax(
    const ushort* __restrict__ ACC, const float* __restrict__ denom,
    const float* __restrict__ b, float* __restrict__ OUT, int n)
{
    int node = blockIdx.x * 4 + (threadIdx.x >> 6);
    if (node >= n) return;
    int lane = threadIdx.x & 63;
    float v = bf2f(ACC[(size_t)node * 64 + lane]) / (denom[node] + 1e-16f) + b[lane];
    float m = v;
    #pragma unroll
    for (int off = 1; off < 64; off <<= 1) m = fmaxf(m, __shfl_xor(m, off));
    float ex = __expf(v - m);
    float sum = ex;
    #pragma unroll
    for (int off = 1; off < 64; off <<= 1) sum += __shfl_xor(sum, off);
    OUT[(size_t)node * 64 + lane] = v - m - __logf(sum);
}

extern "C" void kernel_launch(void* const* d_in, const int* in_sizes, int n_in,
                              void* d_out, int out_size, void* d_ws, size_t ws_size,
                              hipStream_t stream)
{
    const float* x    = (const float*)d_in[0];
    const int*   ei   = (const int*)d_in[1];
    const float* W1   = (const float*)d_in[2];
    const float* as1w = (const float*)d_in[3];
    const float* ad1w = (const float*)d_in[4];
    const float* b1   = (const float*)d_in[5];
    const float* W2   = (const float*)d_in[6];
    const float* as2w = (const float*)d_in[7];
    const float* ad2w = (const float*)d_in[8];
    const float* b2   = (const float*)d_in[9];
    float* out = (float*)d_out;

    const int n  = in_sizes[0] / 256;     // 100000
    const int E_ = in_sizes[1] / 2;       // 1600000
    const int ET = E_ + n;

    char* wsb = (char*)d_ws;
    float*  B    = (float*)wsb;                          // [n*64] f32 (h_act)
    ushort* HB   = (ushort*)(B + (size_t)n * 64);        // [n*64] bf16
    ushort* ACC  = HB + (size_t)n * 64;                  // [n*64] bf16 accumulator
    float*  a_s1 = (float*)(ACC + (size_t)n * 64);       // [n*8]
    float*  a_d1 = a_s1 + (size_t)n * 8;                 // [n*8]
    float*  dn1  = a_d1 + (size_t)n * 8;                 // [n*8]
    float*  a_s2 = dn1 + (size_t)n * 8;                  // [n]
    float*  a_d2 = a_s2 + n;                             // [n]
    float*  dn2  = a_d2 + n;                             // [n]

    const int gemm_grid = (n + 63) / 64;
    const int edge_grid = (ET + 7) / 8;

    // ---- layer 1 ----
    hipMemsetAsync(dn1, 0, (size_t)n * 8 * sizeof(float), stream);
    hipMemsetAsync(ACC, 0, (size_t)n * 64 * sizeof(ushort), stream);
    gemm_bf16out<256><<<gemm_grid, 256, 0, stream>>>(x, W1, HB, n);
    node_att_h8<<<(n + 3) / 4, 256, 0, stream>>>(HB, as1w, ad1w, a_s1, a_d1, n);
    edge_fused_h8<<<edge_grid, 256, 0, stream>>>(ei, E_, ET, a_s1, a_d1, dn1, HB, ACC);
    norm_bias_elu<<<(n * 32 + 255) / 256, 256, 0, stream>>>(ACC, dn1, b1, B, n);

    // ---- layer 2 ----
    gemm_bf16out<64><<<gemm_grid, 256, 0, stream>>>(B, W2, HB, n);
    node_att_h1<<<(n + 3) / 4, 256, 0, stream>>>(HB, as2w, ad2w, a_s2, a_d2, n);
    hipMemsetAsync(dn2, 0, (size_t)n * sizeof(float), stream);
    hipMemsetAsync(ACC, 0, (size_t)n * 64 * sizeof(ushort), stream);
    edge_fused_h1<<<edge_grid, 256, 0, stream>>>(ei, E_, ET, a_s2, a_d2, dn2, HB, ACC);
    norm_bias_logsoftmax<<<(n + 3) / 4, 256, 0, stream>>>(ACC, dn2, b2, out, n);
}

// Round 3
// 469.720 us; speedup vs baseline: 2.2803x; 1.4233x over previous
//
#include <hip/hip_runtime.h>
#include <hip/hip_bf16.h>

#define LRELU_SLOPE 0.2f

typedef unsigned int uint;
typedef unsigned short ushort;

__device__ __forceinline__ float lrelu(float a) {
    return a > 0.f ? a : LRELU_SLOPE * a;
}
__device__ __forceinline__ ushort f2bf(float f) {   // RNE
    uint u = __float_as_uint(f);
    return (ushort)((u + 0x7FFF + ((u >> 16) & 1)) >> 16);
}
__device__ __forceinline__ float bf2f(ushort h) {
    return __uint_as_float(((uint)h) << 16);
}

// ---------------- GEMM: X[nrows,K] @ W[K,64] -> OUT[nrows,64] in bf16 ----------------
template<int K>
__global__ __launch_bounds__(256) void gemm_bf16out(
    const float* __restrict__ X, const float* __restrict__ W,
    ushort* __restrict__ OUT, int nrows)
{
    __shared__ float xs[64][33];
    __shared__ float ws[32][64];
    const int tid = threadIdx.x;
    const int block_row = blockIdx.x * 64;
    const int tx = tid & 15, ty = tid >> 4;
    float acc[4][4] = {};

    for (int k0 = 0; k0 < K; k0 += 32) {
        #pragma unroll
        for (int half = 0; half < 2; ++half) {
            int r = (tid >> 3) + 32 * half;
            int kq = (tid & 7) * 4;
            int gr = block_row + r;
            float4 v = make_float4(0.f, 0.f, 0.f, 0.f);
            if (gr < nrows) v = *(const float4*)(X + (size_t)gr * K + k0 + kq);
            xs[r][kq + 0] = v.x; xs[r][kq + 1] = v.y;
            xs[r][kq + 2] = v.z; xs[r][kq + 3] = v.w;
        }
        #pragma unroll
        for (int half = 0; half < 2; ++half) {
            int i = tid + 256 * half;
            int r = i >> 4, cq = (i & 15) << 2;
            float4 w = *(const float4*)(W + (size_t)(k0 + r) * 64 + cq);
            *(float4*)&ws[r][cq] = w;
        }
        __syncthreads();
        #pragma unroll
        for (int kk = 0; kk < 32; ++kk) {
            float4 wv = *(const float4*)&ws[kk][tx << 2];
            float xr[4];
            #pragma unroll
            for (int i = 0; i < 4; ++i) xr[i] = xs[(ty << 2) + i][kk];
            #pragma unroll
            for (int i = 0; i < 4; ++i) {
                acc[i][0] += xr[i] * wv.x; acc[i][1] += xr[i] * wv.y;
                acc[i][2] += xr[i] * wv.z; acc[i][3] += xr[i] * wv.w;
            }
        }
        __syncthreads();
    }
    #pragma unroll
    for (int i = 0; i < 4; ++i) {
        int gr = block_row + (ty << 2) + i;
        if (gr < nrows) {
            uint2 o;
            o.x = (uint)f2bf(acc[i][0]) | ((uint)f2bf(acc[i][1]) << 16);
            o.y = (uint)f2bf(acc[i][2]) | ((uint)f2bf(acc[i][3]) << 16);
            *(uint2*)(OUT + (size_t)gr * 64 + (tx << 2)) = o;
        }
    }
}

// ---------------- per-node attention logits ----------------
__global__ __launch_bounds__(256) void node_att_h8(
    const ushort* __restrict__ H, const float* __restrict__ att_s,
    const float* __restrict__ att_d,
    float* __restrict__ a_src, float* __restrict__ a_dst, int n)
{
    int node = blockIdx.x * 4 + (threadIdx.x >> 6);
    if (node >= n) return;
    int lane = threadIdx.x & 63;
    float h = bf2f(H[(size_t)node * 64 + lane]);
    float ps = h * att_s[lane];
    float pd = h * att_d[lane];
    #pragma unroll
    for (int off = 1; off < 8; off <<= 1) {
        ps += __shfl_xor(ps, off, 64);
        pd += __shfl_xor(pd, off, 64);
    }
    if ((lane & 7) == 0) {
        a_src[(size_t)node * 8 + (lane >> 3)] = ps;
        a_dst[(size_t)node * 8 + (lane >> 3)] = pd;
    }
}

__global__ __launch_bounds__(256) void node_att_h1(
    const ushort* __restrict__ H, const float* __restrict__ att_s,
    const float* __restrict__ att_d,
    float* __restrict__ a_src, float* __restrict__ a_dst, int n)
{
    int node = blockIdx.x * 4 + (threadIdx.x >> 6);
    if (node >= n) return;
    int lane = threadIdx.x & 63;
    float h = bf2f(H[(size_t)node * 64 + lane]);
    float ps = h * att_s[lane];
    float pd = h * att_d[lane];
    #pragma unroll
    for (int off = 1; off < 64; off <<= 1) {
        ps += __shfl_xor(ps, off, 64);
        pd += __shfl_xor(pd, off, 64);
    }
    if (lane == 0) { a_src[node] = ps; a_dst[node] = pd; }
}

// ---------------- CSR build: histogram, scan (3 kernels), scatter ----------------
__global__ __launch_bounds__(256) void edge_hist(
    const int* __restrict__ ei, int E_, int ET, int* __restrict__ deg)
{
    int e = blockIdx.x * 256 + threadIdx.x;
    if (e >= ET) return;
    int d = (e < E_) ? ei[E_ + e] : e - E_;
    atomicAdd(&deg[d], 1);
}

// block-of-1024 partial sums
__global__ __launch_bounds__(256) void scan_block_sums(
    const int* __restrict__ deg, int* __restrict__ bsums, int n)
{
    int b = blockIdx.x, t = threadIdx.x;
    int base = b * 1024 + t * 4;
    int v = 0;
    #pragma unroll
    for (int i = 0; i < 4; ++i) { int idx = base + i; if (idx < n) v += deg[idx]; }
    __shared__ int sm[256];
    sm[t] = v; __syncthreads();
    for (int s = 128; s > 0; s >>= 1) { if (t < s) sm[t] += sm[t + s]; __syncthreads(); }
    if (t == 0) bsums[b] = sm[0];
}

// exclusive scan of block sums (nb <= 256), single block
__global__ __launch_bounds__(256) void scan_bsums(int* __restrict__ bsums, int nb)
{
    __shared__ int sm[256];
    int t = threadIdx.x;
    int orig = (t < nb) ? bsums[t] : 0;
    sm[t] = orig; __syncthreads();
    for (int off = 1; off < 256; off <<= 1) {
        int v = (t >= off) ? sm[t - off] : 0;
        __syncthreads();
        sm[t] += v;
        __syncthreads();
    }
    if (t < nb) bsums[t] = sm[t] - orig;
}

// write exclusive prefix into rp
__global__ __launch_bounds__(256) void scan_write(
    const int* __restrict__ deg, const int* __restrict__ bsums,
    int* __restrict__ rp, int n)
{
    int b = blockIdx.x, t = threadIdx.x;
    int base = b * 1024 + t * 4;
    int loc[4]; int s = 0;
    #pragma unroll
    for (int i = 0; i < 4; ++i) {
        int idx = base + i;
        loc[i] = (idx < n) ? deg[idx] : 0;
        s += loc[i];
    }
    __shared__ int sm[256];
    int orig = s;
    sm[t] = s; __syncthreads();
    for (int off = 1; off < 256; off <<= 1) {
        int v = (t >= off) ? sm[t - off] : 0;
        __syncthreads();
        sm[t] += v;
        __syncthreads();
    }
    int run = sm[t] - orig + bsums[b];
    #pragma unroll
    for (int i = 0; i < 4; ++i) {
        int idx = base + i;
        if (idx < n) rp[idx] = run;
        run += loc[i];
    }
}

// scatter src ids into dst-sorted order; rp[d] advances from start_d to end_d
__global__ __launch_bounds__(256) void edge_scatter_build(
    const int* __restrict__ ei, int E_, int ET,
    int* __restrict__ rp, int* __restrict__ ssrc)
{
    int e = blockIdx.x * 256 + threadIdx.x;
    if (e >= ET) return;
    int s, d;
    if (e < E_) { s = ei[e]; d = ei[E_ + e]; } else { s = d = e - E_; }
    int pos = atomicAdd(&rp[d], 1);
    ssrc[pos] = s;
}

// ---- pull-gather layer 1: wave per node, fused softmax-norm + bias + ELU ----
// rp is post-scatter: rp[d] == end_d; start_d = (d ? rp[d-1] : 0)
__global__ __launch_bounds__(256) void gather_h8(
    const int* __restrict__ rp, const int* __restrict__ ssrc,
    const float* __restrict__ a_src, const float* __restrict__ a_dst,
    const ushort* __restrict__ HB, const float* __restrict__ b,
    float* __restrict__ B, int n)
{
    int node = blockIdx.x * 4 + (threadIdx.x >> 6);
    if (node >= n) return;
    int lane = threadIdx.x & 63;
    int end = rp[node];
    int start = node ? rp[node - 1] : 0;
    int head = lane >> 3;
    float ad = a_dst[(size_t)node * 8 + head];
    float acc = 0.f, dsum = 0.f;

    for (int i0 = start; i0 < end; i0 += 64) {
        int cnt = min(64, end - i0);
        int sv = (i0 + lane < end) ? ssrc[i0 + lane] : 0;
        int j = 0;
        for (; j + 2 <= cnt; j += 2) {
            int s0 = __shfl(sv, j, 64);
            int s1 = __shfl(sv, j + 1, 64);
            float as0 = a_src[(size_t)s0 * 8 + head];
            float as1 = a_src[(size_t)s1 * 8 + head];
            float h0 = bf2f(HB[(size_t)s0 * 64 + lane]);
            float h1 = bf2f(HB[(size_t)s1 * 64 + lane]);
            float ex0 = __expf(lrelu(as0 + ad));
            float ex1 = __expf(lrelu(as1 + ad));
            dsum += ex0 + ex1;
            acc += ex0 * h0 + ex1 * h1;
        }
        if (j < cnt) {
            int s0 = __shfl(sv, j, 64);
            float as0 = a_src[(size_t)s0 * 8 + head];
            float h0 = bf2f(HB[(size_t)s0 * 64 + lane]);
            float ex0 = __expf(lrelu(as0 + ad));
            dsum += ex0;
            acc += ex0 * h0;
        }
    }
    float v = acc / (dsum + 1e-16f) + b[lane];
    B[(size_t)node * 64 + lane] = v > 0.f ? v : expm1f(v);
}

// ---- pull-gather layer 2: wave per node, fused norm + bias + log_softmax ----
__global__ __launch_bounds__(256) void gather_h1_lsm(
    const int* __restrict__ rp, const int* __restrict__ ssrc,
    const float* __restrict__ a_src, const float* __restrict__ a_dst,
    const ushort* __restrict__ HB, const float* __restrict__ b,
    float* __restrict__ OUT, int n)
{
    int node = blockIdx.x * 4 + (threadIdx.x >> 6);
    if (node >= n) return;
    int lane = threadIdx.x & 63;
    int end = rp[node];
    int start = node ? rp[node - 1] : 0;
    float ad = a_dst[node];
    float acc = 0.f, dsum = 0.f;

    for (int i0 = start; i0 < end; i0 += 64) {
        int cnt = min(64, end - i0);
        int sv = (i0 + lane < end) ? ssrc[i0 + lane] : 0;
        int j = 0;
        for (; j + 2 <= cnt; j += 2) {
            int s0 = __shfl(sv, j, 64);
            int s1 = __shfl(sv, j + 1, 64);
            float as0 = a_src[s0];
            float as1 = a_src[s1];
            float h0 = bf2f(HB[(size_t)s0 * 64 + lane]);
            float h1 = bf2f(HB[(size_t)s1 * 64 + lane]);
            float ex0 = __expf(lrelu(as0 + ad));
            float ex1 = __expf(lrelu(as1 + ad));
            dsum += ex0 + ex1;
            acc += ex0 * h0 + ex1 * h1;
        }
        if (j < cnt) {
            int s0 = __shfl(sv, j, 64);
            float as0 = a_src[s0];
            float h0 = bf2f(HB[(size_t)s0 * 64 + lane]);
            float ex0 = __expf(lrelu(as0 + ad));
            dsum += ex0;
            acc += ex0 * h0;
        }
    }
    float v = acc / (dsum + 1e-16f) + b[lane];
    float m = v;
    #pragma unroll
    for (int off = 1; off < 64; off <<= 1) m = fmaxf(m, __shfl_xor(m, off));
    float ex = __expf(v - m);
    float sum = ex;
    #pragma unroll
    for (int off = 1; off < 64; off <<= 1) sum += __shfl_xor(sum, off);
    OUT[(size_t)node * 64 + lane] = v - m - __logf(sum);
}

extern "C" void kernel_launch(void* const* d_in, const int* in_sizes, int n_in,
                              void* d_out, int out_size, void* d_ws, size_t ws_size,
                              hipStream_t stream)
{
    const float* x    = (const float*)d_in[0];
    const int*   ei   = (const int*)d_in[1];
    const float* W1   = (const float*)d_in[2];
    const float* as1w = (const float*)d_in[3];
    const float* ad1w = (const float*)d_in[4];
    const float* b1   = (const float*)d_in[5];
    const float* W2   = (const float*)d_in[6];
    const float* as2w = (const float*)d_in[7];
    const float* ad2w = (const float*)d_in[8];
    const float* b2   = (const float*)d_in[9];
    float* out = (float*)d_out;

    const int n  = in_sizes[0] / 256;     // 100000
    const int E_ = in_sizes[1] / 2;       // 1600000
    const int ET = E_ + n;
    const int NB = (n + 1023) / 1024;     // scan blocks (98)

    char* wsb = (char*)d_ws;
    float*  B    = (float*)wsb;                          // [n*64] f32
    ushort* HB   = (ushort*)(B + (size_t)n * 64);        // [n*64] bf16
    float*  a_s1 = (float*)(HB + (size_t)n * 64);        // [n*8]
    float*  a_d1 = a_s1 + (size_t)n * 8;                 // [n*8]
    float*  a_s2 = a_d1 + (size_t)n * 8;                 // [n]
    float*  a_d2 = a_s2 + n;                             // [n]
    int*    deg  = (int*)(a_d2 + n);                     // [n]
    int*    rp   = deg + n;                              // [n]
    int*    bsums= rp + n;                               // [256]
    int*    ssrc = bsums + 256;                          // [ET]

    const int gemm_grid = (n + 63) / 64;
    const int edge_grid = (ET + 255) / 256;
    const int node_grid = (n + 3) / 4;

    // ---- CSR build (reused by both layers) ----
    hipMemsetAsync(deg, 0, (size_t)n * sizeof(int), stream);
    edge_hist<<<edge_grid, 256, 0, stream>>>(ei, E_, ET, deg);
    scan_block_sums<<<NB, 256, 0, stream>>>(deg, bsums, n);
    scan_bsums<<<1, 256, 0, stream>>>(bsums, NB);
    scan_write<<<NB, 256, 0, stream>>>(deg, bsums, rp, n);
    edge_scatter_build<<<edge_grid, 256, 0, stream>>>(ei, E_, ET, rp, ssrc);

    // ---- layer 1 ----
    gemm_bf16out<256><<<gemm_grid, 256, 0, stream>>>(x, W1, HB, n);
    node_att_h8<<<node_grid, 256, 0, stream>>>(HB, as1w, ad1w, a_s1, a_d1, n);
    gather_h8<<<node_grid, 256, 0, stream>>>(rp, ssrc, a_s1, a_d1, HB, b1, B, n);

    // ---- layer 2 ----
    gemm_bf16out<64><<<gemm_grid, 256, 0, stream>>>(B, W2, HB, n);
    node_att_h1<<<node_grid, 256, 0, stream>>>(HB, as2w, ad2w, a_s2, a_d2, n);
    gather_h1_lsm<<<node_grid, 256, 0, stream>>>(rp, ssrc, a_s2, a_d2, HB, b2, out, n);
}

// Round 4
// 412.418 us; speedup vs baseline: 2.5972x; 1.1389x over previous
//
#include <hip/hip_runtime.h>
#include <hip/hip_bf16.h>

#define LRELU_SLOPE 0.2f
#define CH 12288          // edges staged per partition block
#define NBUK 128          // dst buckets (1024 nodes each)
#define BCAP 18432        // per-bucket capacity (mean 17408, +8 sigma)

typedef unsigned int uint;
typedef unsigned short ushort;

__device__ __forceinline__ float lrelu(float a) {
    return a > 0.f ? a : LRELU_SLOPE * a;
}
__device__ __forceinline__ ushort f2bf(float f) {   // RNE
    uint u = __float_as_uint(f);
    return (ushort)((u + 0x7FFF + ((u >> 16) & 1)) >> 16);
}
__device__ __forceinline__ float bf2f(ushort h) {
    return __uint_as_float(((uint)h) << 16);
}

// ---------------- GEMM: X[nrows,K] @ W[K,64] -> OUT[nrows,64] in bf16 ----------------
template<int K>
__global__ __launch_bounds__(256) void gemm_bf16out(
    const float* __restrict__ X, const float* __restrict__ W,
    ushort* __restrict__ OUT, int nrows)
{
    __shared__ float xs[64][33];
    __shared__ float ws[32][64];
    const int tid = threadIdx.x;
    const int block_row = blockIdx.x * 64;
    const int tx = tid & 15, ty = tid >> 4;
    float acc[4][4] = {};

    for (int k0 = 0; k0 < K; k0 += 32) {
        #pragma unroll
        for (int half = 0; half < 2; ++half) {
            int r = (tid >> 3) + 32 * half;
            int kq = (tid & 7) * 4;
            int gr = block_row + r;
            float4 v = make_float4(0.f, 0.f, 0.f, 0.f);
            if (gr < nrows) v = *(const float4*)(X + (size_t)gr * K + k0 + kq);
            xs[r][kq + 0] = v.x; xs[r][kq + 1] = v.y;
            xs[r][kq + 2] = v.z; xs[r][kq + 3] = v.w;
        }
        #pragma unroll
        for (int half = 0; half < 2; ++half) {
            int i = tid + 256 * half;
            int r = i >> 4, cq = (i & 15) << 2;
            float4 w = *(const float4*)(W + (size_t)(k0 + r) * 64 + cq);
            *(float4*)&ws[r][cq] = w;
        }
        __syncthreads();
        #pragma unroll
        for (int kk = 0; kk < 32; ++kk) {
            float4 wv = *(const float4*)&ws[kk][tx << 2];
            float xr[4];
            #pragma unroll
            for (int i = 0; i < 4; ++i) xr[i] = xs[(ty << 2) + i][kk];
            #pragma unroll
            for (int i = 0; i < 4; ++i) {
                acc[i][0] += xr[i] * wv.x; acc[i][1] += xr[i] * wv.y;
                acc[i][2] += xr[i] * wv.z; acc[i][3] += xr[i] * wv.w;
            }
        }
        __syncthreads();
    }
    #pragma unroll
    for (int i = 0; i < 4; ++i) {
        int gr = block_row + (ty << 2) + i;
        if (gr < nrows) {
            uint2 o;
            o.x = (uint)f2bf(acc[i][0]) | ((uint)f2bf(acc[i][1]) << 16);
            o.y = (uint)f2bf(acc[i][2]) | ((uint)f2bf(acc[i][3]) << 16);
            *(uint2*)(OUT + (size_t)gr * 64 + (tx << 2)) = o;
        }
    }
}

// ---------------- per-node attention logits ----------------
__global__ __launch_bounds__(256) void node_att_h8(
    const ushort* __restrict__ H, const float* __restrict__ att_s,
    const float* __restrict__ att_d,
    float* __restrict__ a_src, float* __restrict__ a_dst, int n)
{
    int node = blockIdx.x * 4 + (threadIdx.x >> 6);
    if (node >= n) return;
    int lane = threadIdx.x & 63;
    float h = bf2f(H[(size_t)node * 64 + lane]);
    float ps = h * att_s[lane];
    float pd = h * att_d[lane];
    #pragma unroll
    for (int off = 1; off < 8; off <<= 1) {
        ps += __shfl_xor(ps, off, 64);
        pd += __shfl_xor(pd, off, 64);
    }
    if ((lane & 7) == 0) {
        a_src[(size_t)node * 8 + (lane >> 3)] = ps;
        a_dst[(size_t)node * 8 + (lane >> 3)] = pd;
    }
}

__global__ __launch_bounds__(256) void node_att_h1(
    const ushort* __restrict__ H, const float* __restrict__ att_s,
    const float* __restrict__ att_d,
    float* __restrict__ a_src, float* __restrict__ a_dst, int n)
{
    int node = blockIdx.x * 4 + (threadIdx.x >> 6);
    if (node >= n) return;
    int lane = threadIdx.x & 63;
    float h = bf2f(H[(size_t)node * 64 + lane]);
    float ps = h * att_s[lane];
    float pd = h * att_d[lane];
    #pragma unroll
    for (int off = 1; off < 64; off <<= 1) {
        ps += __shfl_xor(ps, off, 64);
        pd += __shfl_xor(pd, off, 64);
    }
    if (lane == 0) { a_src[node] = ps; a_dst[node] = pd; }
}

// ---------------- init per-bucket cursors ----------------
__global__ void init_pcur(int* __restrict__ pcur)
{
    int t = threadIdx.x;
    if (t < NBUK) pcur[t] = t * BCAP;
}

// ---- phase 1: LDS-binned partition of edges into dst buckets; also builds deg ----
__global__ __launch_bounds__(256) void partition_pairs(
    const int* __restrict__ ei, int E_, int ET,
    int* __restrict__ deg, int* __restrict__ pcur, uint* __restrict__ pairs)
{
    __shared__ uint lpair[CH];
    __shared__ int lcnt[NBUK], sc[NBUK], lstart[NBUK], lplace[NBUK], gpos[NBUK];
    const int t = threadIdx.x;
    const int base = blockIdx.x * CH;
    const int total = min(CH, ET - base);
    if (total <= 0) return;

    if (t < NBUK) lcnt[t] = 0;
    __syncthreads();

    // count pass (also global degree histogram)
    for (int i = t; i < total; i += 256) {
        int e = base + i;
        int d = (e < E_) ? ei[E_ + e] : e - E_;
        atomicAdd(&lcnt[d >> 10], 1);
        atomicAdd(&deg[d], 1);
    }
    __syncthreads();

    // exclusive scan of lcnt -> lstart
    if (t < NBUK) sc[t] = lcnt[t];
    __syncthreads();
    for (int off = 1; off < NBUK; off <<= 1) {
        int v = 0;
        if (t < NBUK && t >= off) v = sc[t - off];
        __syncthreads();
        if (t < NBUK) sc[t] += v;
        __syncthreads();
    }
    if (t < NBUK) { lstart[t] = sc[t] - lcnt[t]; lplace[t] = sc[t] - lcnt[t]; }
    __syncthreads();

    // placement pass: bucket-ordered into LDS
    for (int i = t; i < total; i += 256) {
        int e = base + i;
        int s, d;
        if (e < E_) { s = ei[e]; d = ei[E_ + e]; } else { s = d = e - E_; }
        int k = d >> 10;
        int slot = atomicAdd(&lplace[k], 1);
        lpair[slot] = (uint)s | ((uint)(d & 1023) << 17);
    }
    __syncthreads();

    // reserve global runs
    if (t < NBUK) {
        int c = lcnt[t];
        gpos[t] = c ? atomicAdd(&pcur[t], c) : 0;
    }
    __syncthreads();

    // flush: binary search bucket of each LDS slot, contiguous run writes
    for (int i = t; i < total; i += 256) {
        int lo = 0, hi = NBUK - 1;
        while (lo < hi) {
            int mid = (lo + hi + 1) >> 1;
            if (lstart[mid] <= i) lo = mid; else hi = mid - 1;
        }
        pairs[gpos[lo] + (i - lstart[lo])] = lpair[i];
    }
}

// ---------------- scan: block partial sums ----------------
__global__ __launch_bounds__(256) void scan_block_sums(
    const int* __restrict__ deg, int* __restrict__ bsums, int n)
{
    int b = blockIdx.x, t = threadIdx.x;
    int base = b * 1024 + t * 4;
    int v = 0;
    #pragma unroll
    for (int i = 0; i < 4; ++i) { int idx = base + i; if (idx < n) v += deg[idx]; }
    __shared__ int sm[256];
    sm[t] = v; __syncthreads();
    for (int s = 128; s > 0; s >>= 1) { if (t < s) sm[t] += sm[t + s]; __syncthreads(); }
    if (t == 0) bsums[b] = sm[0];
}

__global__ __launch_bounds__(256) void scan_bsums(int* __restrict__ bsums, int nb)
{
    __shared__ int sm[256];
    int t = threadIdx.x;
    int orig = (t < nb) ? bsums[t] : 0;
    sm[t] = orig; __syncthreads();
    for (int off = 1; off < 256; off <<= 1) {
        int v = (t >= off) ? sm[t - off] : 0;
        __syncthreads();
        sm[t] += v;
        __syncthreads();
    }
    if (t < nb) bsums[t] = sm[t] - orig;
}

__global__ __launch_bounds__(256) void scan_write(
    const int* __restrict__ deg, const int* __restrict__ bsums,
    int* __restrict__ rp, int n)
{
    int b = blockIdx.x, t = threadIdx.x;
    int base = b * 1024 + t * 4;
    int loc[4]; int s = 0;
    #pragma unroll
    for (int i = 0; i < 4; ++i) {
        int idx = base + i;
        loc[i] = (idx < n) ? deg[idx] : 0;
        s += loc[i];
    }
    __shared__ int sm[256];
    int orig = s;
    sm[t] = s; __syncthreads();
    for (int off = 1; off < 256; off <<= 1) {
        int v = (t >= off) ? sm[t - off] : 0;
        __syncthreads();
        sm[t] += v;
        __syncthreads();
    }
    int run = sm[t] - orig + bsums[b];
    #pragma unroll
    for (int i = 0; i < 4; ++i) {
        int idx = base + i;
        if (idx < n) rp[idx] = run;
        run += loc[i];
    }
}

// ---- phase 2: per-bucket CSR scatter (one workgroup per bucket, L2-confined) ----
__global__ __launch_bounds__(1024) void phase2_scatter(
    const uint* __restrict__ pairs, const int* __restrict__ pcur,
    int* __restrict__ rp, int* __restrict__ ssrc)
{
    int k = blockIdx.x;
    int beg = k * BCAP;
    int end = pcur[k];
    int dbase = k << 10;
    for (int i = beg + threadIdx.x; i < end; i += 1024) {
        uint p = pairs[i];
        int d = dbase + (int)(p >> 17);
        int s = (int)(p & 0x1FFFF);
        int pos = atomicAdd(&rp[d], 1);
        ssrc[pos] = s;
    }
}

// ---- pull-gather layer 1: wave per node, fused softmax-norm + bias + ELU ----
__global__ __launch_bounds__(256) void gather_h8(
    const int* __restrict__ rp, const int* __restrict__ ssrc,
    const float* __restrict__ a_src, const float* __restrict__ a_dst,
    const ushort* __restrict__ HB, const float* __restrict__ b,
    float* __restrict__ B, int n)
{
    int node = blockIdx.x * 4 + (threadIdx.x >> 6);
    if (node >= n) return;
    int lane = threadIdx.x & 63;
    int end = rp[node];
    int start = node ? rp[node - 1] : 0;
    int head = lane >> 3;
    float ad = a_dst[(size_t)node * 8 + head];
    float acc = 0.f, dsum = 0.f;

    for (int i0 = start; i0 < end; i0 += 64) {
        int cnt = min(64, end - i0);
        int sv = (i0 + lane < end) ? ssrc[i0 + lane] : 0;
        int j = 0;
        for (; j + 4 <= cnt; j += 4) {
            int s0 = __shfl(sv, j, 64);
            int s1 = __shfl(sv, j + 1, 64);
            int s2 = __shfl(sv, j + 2, 64);
            int s3 = __shfl(sv, j + 3, 64);
            float as0 = a_src[(size_t)s0 * 8 + head];
            float as1 = a_src[(size_t)s1 * 8 + head];
            float as2 = a_src[(size_t)s2 * 8 + head];
            float as3 = a_src[(size_t)s3 * 8 + head];
            float h0 = bf2f(HB[(size_t)s0 * 64 + lane]);
            float h1 = bf2f(HB[(size_t)s1 * 64 + lane]);
            float h2 = bf2f(HB[(size_t)s2 * 64 + lane]);
            float h3 = bf2f(HB[(size_t)s3 * 64 + lane]);
            float ex0 = __expf(lrelu(as0 + ad));
            float ex1 = __expf(lrelu(as1 + ad));
            float ex2 = __expf(lrelu(as2 + ad));
            float ex3 = __expf(lrelu(as3 + ad));
            dsum += (ex0 + ex1) + (ex2 + ex3);
            acc += ex0 * h0 + ex1 * h1 + ex2 * h2 + ex3 * h3;
        }
        for (; j < cnt; ++j) {
            int s0 = __shfl(sv, j, 64);
            float as0 = a_src[(size_t)s0 * 8 + head];
            float h0 = bf2f(HB[(size_t)s0 * 64 + lane]);
            float ex0 = __expf(lrelu(as0 + ad));
            dsum += ex0;
            acc += ex0 * h0;
        }
    }
    float v = acc / (dsum + 1e-16f) + b[lane];
    B[(size_t)node * 64 + lane] = v > 0.f ? v : expm1f(v);
}

// ---- pull-gather layer 2: wave per node, fused norm + bias + log_softmax ----
__global__ __launch_bounds__(256) void gather_h1_lsm(
    const int* __restrict__ rp, const int* __restrict__ ssrc,
    const float* __restrict__ a_src, const float* __restrict__ a_dst,
    const ushort* __restrict__ HB, const float* __restrict__ b,
    float* __restrict__ OUT, int n)
{
    int node = blockIdx.x * 4 + (threadIdx.x >> 6);
    if (node >= n) return;
    int lane = threadIdx.x & 63;
    int end = rp[node];
    int start = node ? rp[node - 1] : 0;
    float ad = a_dst[node];
    float acc = 0.f, dsum = 0.f;

    for (int i0 = start; i0 < end; i0 += 64) {
        int cnt = min(64, end - i0);
        int sv = (i0 + lane < end) ? ssrc[i0 + lane] : 0;
        int j = 0;
        for (; j + 4 <= cnt; j += 4) {
            int s0 = __shfl(sv, j, 64);
            int s1 = __shfl(sv, j + 1, 64);
            int s2 = __shfl(sv, j + 2, 64);
            int s3 = __shfl(sv, j + 3, 64);
            float as0 = a_src[s0];
            float as1 = a_src[s1];
            float as2 = a_src[s2];
            float as3 = a_src[s3];
            float h0 = bf2f(HB[(size_t)s0 * 64 + lane]);
            float h1 = bf2f(HB[(size_t)s1 * 64 + lane]);
            float h2 = bf2f(HB[(size_t)s2 * 64 + lane]);
            float h3 = bf2f(HB[(size_t)s3 * 64 + lane]);
            float ex0 = __expf(lrelu(as0 + ad));
            float ex1 = __expf(lrelu(as1 + ad));
            float ex2 = __expf(lrelu(as2 + ad));
            float ex3 = __expf(lrelu(as3 + ad));
            dsum += (ex0 + ex1) + (ex2 + ex3);
            acc += ex0 * h0 + ex1 * h1 + ex2 * h2 + ex3 * h3;
        }
        for (; j < cnt; ++j) {
            int s0 = __shfl(sv, j, 64);
            float as0 = a_src[s0];
            float h0 = bf2f(HB[(size_t)s0 * 64 + lane]);
            float ex0 = __expf(lrelu(as0 + ad));
            dsum += ex0;
            acc += ex0 * h0;
        }
    }
    float v = acc / (dsum + 1e-16f) + b[lane];
    float m = v;
    #pragma unroll
    for (int off = 1; off < 64; off <<= 1) m = fmaxf(m, __shfl_xor(m, off));
    float ex = __expf(v - m);
    float sum = ex;
    #pragma unroll
    for (int off = 1; off < 64; off <<= 1) sum += __shfl_xor(sum, off);
    OUT[(size_t)node * 64 + lane] = v - m - __logf(sum);
}

extern "C" void kernel_launch(void* const* d_in, const int* in_sizes, int n_in,
                              void* d_out, int out_size, void* d_ws, size_t ws_size,
                              hipStream_t stream)
{
    const float* x    = (const float*)d_in[0];
    const int*   ei   = (const int*)d_in[1];
    const float* W1   = (const float*)d_in[2];
    const float* as1w = (const float*)d_in[3];
    const float* ad1w = (const float*)d_in[4];
    const float* b1   = (const float*)d_in[5];
    const float* W2   = (const float*)d_in[6];
    const float* as2w = (const float*)d_in[7];
    const float* ad2w = (const float*)d_in[8];
    const float* b2   = (const float*)d_in[9];
    float* out = (float*)d_out;

    const int n  = in_sizes[0] / 256;     // 100000
    const int E_ = in_sizes[1] / 2;       // 1600000
    const int ET = E_ + n;
    const int NB = (n + 1023) / 1024;     // 98 scan blocks
    const int NBUKU = (n + 1023) >> 10;   // 98 used buckets

    char* wsb = (char*)d_ws;
    float*  B    = (float*)wsb;                          // [n*64] f32 (aliases pairs)
    uint*   pairs= (uint*)wsb;                           // [NBUK*BCAP] (build-time only)
    ushort* HB   = (ushort*)(B + (size_t)n * 64);        // [n*64] bf16
    float*  a_s1 = (float*)(HB + (size_t)n * 64);        // [n*8]
    float*  a_d1 = a_s1 + (size_t)n * 8;                 // [n*8]
    float*  a_s2 = a_d1 + (size_t)n * 8;                 // [n]
    float*  a_d2 = a_s2 + n;                             // [n]
    int*    deg  = (int*)(a_d2 + n);                     // [n]
    int*    rp   = deg + n;                              // [n]
    int*    bsums= rp + n;                               // [256]
    int*    pcur = bsums + 256;                          // [NBUK]
    int*    ssrc = pcur + NBUK;                          // [ET]

    const int gemm_grid = (n + 63) / 64;
    const int node_grid = (n + 3) / 4;
    const int part_grid = (ET + CH - 1) / CH;

    // ---- CSR build (reused by both layers) ----
    hipMemsetAsync(deg, 0, (size_t)n * sizeof(int), stream);
    init_pcur<<<1, 128, 0, stream>>>(pcur);
    partition_pairs<<<part_grid, 256, 0, stream>>>(ei, E_, ET, deg, pcur, pairs);
    scan_block_sums<<<NB, 256, 0, stream>>>(deg, bsums, n);
    scan_bsums<<<1, 256, 0, stream>>>(bsums, NB);
    scan_write<<<NB, 256, 0, stream>>>(deg, bsums, rp, n);
    phase2_scatter<<<NBUKU, 1024, 0, stream>>>(pairs, pcur, rp, ssrc);

    // ---- layer 1 ----
    gemm_bf16out<256><<<gemm_grid, 256, 0, stream>>>(x, W1, HB, n);
    node_att_h8<<<node_grid, 256, 0, stream>>>(HB, as1w, ad1w, a_s1, a_d1, n);
    gather_h8<<<node_grid, 256, 0, stream>>>(rp, ssrc, a_s1, a_d1, HB, b1, B, n);

    // ---- layer 2 ----
    gemm_bf16out<64><<<gemm_grid, 256, 0, stream>>>(B, W2, HB, n);
    node_att_h1<<<node_grid, 256, 0, stream>>>(HB, as2w, ad2w, a_s2, a_d2, n);
    gather_h1_lsm<<<node_grid, 256, 0, stream>>>(rp, ssrc, a_s2, a_d2, HB, b2, out, n);
}

// Round 5
// 282.458 us; speedup vs baseline: 3.7921x; 1.4601x over previous
//
#include <hip/hip_runtime.h>
#include <hip/hip_bf16.h>

#define LRELU_SLOPE 0.2f
#define CH2 6144          // edges per partition block (6 per thread, 1024 threads)
#define NBUK 256          // dst buckets (512 nodes each)
#define BCAP 9728         // per-bucket capacity (mean 8704, +11 sigma)

typedef unsigned int uint;
typedef unsigned short ushort;

__device__ __forceinline__ float lrelu(float a) {
    return a > 0.f ? a : LRELU_SLOPE * a;
}
__device__ __forceinline__ ushort f2bf(float f) {   // RNE
    uint u = __float_as_uint(f);
    return (ushort)((u + 0x7FFF + ((u >> 16) & 1)) >> 16);
}
__device__ __forceinline__ float bf2f(ushort h) {
    return __uint_as_float(((uint)h) << 16);
}

// ---------------- GEMM: X[nrows,K] @ W[K,64] -> OUT[nrows,64] in bf16 ----------------
template<int K>
__global__ __launch_bounds__(256) void gemm_bf16out(
    const float* __restrict__ X, const float* __restrict__ W,
    ushort* __restrict__ OUT, int nrows)
{
    __shared__ float xs[64][33];
    __shared__ float ws[32][64];
    const int tid = threadIdx.x;
    const int block_row = blockIdx.x * 64;
    const int tx = tid & 15, ty = tid >> 4;
    float acc[4][4] = {};

    for (int k0 = 0; k0 < K; k0 += 32) {
        #pragma unroll
        for (int half = 0; half < 2; ++half) {
            int r = (tid >> 3) + 32 * half;
            int kq = (tid & 7) * 4;
            int gr = block_row + r;
            float4 v = make_float4(0.f, 0.f, 0.f, 0.f);
            if (gr < nrows) v = *(const float4*)(X + (size_t)gr * K + k0 + kq);
            xs[r][kq + 0] = v.x; xs[r][kq + 1] = v.y;
            xs[r][kq + 2] = v.z; xs[r][kq + 3] = v.w;
        }
        #pragma unroll
        for (int half = 0; half < 2; ++half) {
            int i = tid + 256 * half;
            int r = i >> 4, cq = (i & 15) << 2;
            float4 w = *(const float4*)(W + (size_t)(k0 + r) * 64 + cq);
            *(float4*)&ws[r][cq] = w;
        }
        __syncthreads();
        #pragma unroll
        for (int kk = 0; kk < 32; ++kk) {
            float4 wv = *(const float4*)&ws[kk][tx << 2];
            float xr[4];
            #pragma unroll
            for (int i = 0; i < 4; ++i) xr[i] = xs[(ty << 2) + i][kk];
            #pragma unroll
            for (int i = 0; i < 4; ++i) {
                acc[i][0] += xr[i] * wv.x; acc[i][1] += xr[i] * wv.y;
                acc[i][2] += xr[i] * wv.z; acc[i][3] += xr[i] * wv.w;
            }
        }
        __syncthreads();
    }
    #pragma unroll
    for (int i = 0; i < 4; ++i) {
        int gr = block_row + (ty << 2) + i;
        if (gr < nrows) {
            uint2 o;
            o.x = (uint)f2bf(acc[i][0]) | ((uint)f2bf(acc[i][1]) << 16);
            o.y = (uint)f2bf(acc[i][2]) | ((uint)f2bf(acc[i][3]) << 16);
            *(uint2*)(OUT + (size_t)gr * 64 + (tx << 2)) = o;
        }
    }
}

// ---------------- per-node attention logits ----------------
__global__ __launch_bounds__(256) void node_att_h8(
    const ushort* __restrict__ H, const float* __restrict__ att_s,
    const float* __restrict__ att_d,
    float* __restrict__ a_src, float* __restrict__ a_dst, int n)
{
    int node = blockIdx.x * 4 + (threadIdx.x >> 6);
    if (node >= n) return;
    int lane = threadIdx.x & 63;
    float h = bf2f(H[(size_t)node * 64 + lane]);
    float ps = h * att_s[lane];
    float pd = h * att_d[lane];
    #pragma unroll
    for (int off = 1; off < 8; off <<= 1) {
        ps += __shfl_xor(ps, off, 64);
        pd += __shfl_xor(pd, off, 64);
    }
    if ((lane & 7) == 0) {
        a_src[(size_t)node * 8 + (lane >> 3)] = ps;
        a_dst[(size_t)node * 8 + (lane >> 3)] = pd;
    }
}

__global__ __launch_bounds__(256) void node_att_h1(
    const ushort* __restrict__ H, const float* __restrict__ att_s,
    const float* __restrict__ att_d,
    float* __restrict__ a_src, float* __restrict__ a_dst, int n)
{
    int node = blockIdx.x * 4 + (threadIdx.x >> 6);
    if (node >= n) return;
    int lane = threadIdx.x & 63;
    float h = bf2f(H[(size_t)node * 64 + lane]);
    float ps = h * att_s[lane];
    float pd = h * att_d[lane];
    #pragma unroll
    for (int off = 1; off < 64; off <<= 1) {
        ps += __shfl_xor(ps, off, 64);
        pd += __shfl_xor(pd, off, 64);
    }
    if (lane == 0) { a_src[node] = ps; a_dst[node] = pd; }
}

// ---------------- init per-bucket cursors ----------------
__global__ void init_pcur(int* __restrict__ pcur)
{
    int t = threadIdx.x;
    if (t < NBUK) pcur[t] = t * BCAP;
}

// ---- phase 1: register-held partition of edges into dst buckets ----
// pairs entry: src (17b) | dloc (9b, bits 17..25); bucket implied by region.
__global__ __launch_bounds__(1024) void partition_pairs(
    const int* __restrict__ ei, int E_, int ET,
    int* __restrict__ pcur, uint* __restrict__ pairs)
{
    __shared__ int lcnt[NBUK], lsc[NBUK], lplace[NBUK], gpos[NBUK];
    const int t = threadIdx.x;
    const int base = blockIdx.x * CH2;
    const int total = min(CH2, ET - base);
    if (total <= 0) return;

    if (t < NBUK) lcnt[t] = 0;
    __syncthreads();

    // load + count (edges held in registers)
    uint pp[6]; int pk[6];
    #pragma unroll
    for (int i = 0; i < 6; ++i) {
        int idx = t + i * 1024;
        pk[i] = -1;
        if (idx < total) {
            int e = base + idx;
            int s, d;
            if (e < E_) { s = ei[e]; d = ei[E_ + e]; } else { s = d = e - E_; }
            pk[i] = d >> 9;
            pp[i] = (uint)s | ((uint)(d & 511) << 17);
            atomicAdd(&lcnt[pk[i]], 1);
        }
    }
    __syncthreads();

    // inclusive scan of lcnt (t < NBUK active)
    if (t < NBUK) lsc[t] = lcnt[t];
    __syncthreads();
    for (int off = 1; off < NBUK; off <<= 1) {
        int add = 0;
        if (t < NBUK && t >= off) add = lsc[t - off];
        __syncthreads();
        if (t < NBUK) lsc[t] += add;
        __syncthreads();
    }
    // reserve global runs; bias gpos so global index = gpos[k] + slot
    if (t < NBUK) {
        int excl = lsc[t] - lcnt[t];
        lplace[t] = excl;
        int c = lcnt[t];
        gpos[t] = c ? (atomicAdd(&pcur[t], c) - excl) : 0;
    }
    __syncthreads();

    // place: direct global write, address-ordered per (block,bucket) run
    #pragma unroll
    for (int i = 0; i < 6; ++i) {
        if (pk[i] >= 0) {
            int slot = atomicAdd(&lplace[pk[i]], 1);
            pairs[gpos[pk[i]] + slot] = pp[i];
        }
    }
}

// ---- exclusive scan of bucket totals -> boff (single block) ----
__global__ __launch_bounds__(256) void bucket_scan(
    const int* __restrict__ pcur, int* __restrict__ boff, int nbuk_used)
{
    __shared__ int sm[NBUK];
    int t = threadIdx.x;
    int v = (t < nbuk_used) ? (pcur[t] - t * BCAP) : 0;
    sm[t] = v; __syncthreads();
    for (int off = 1; off < NBUK; off <<= 1) {
        int add = (t >= off) ? sm[t - off] : 0;
        __syncthreads();
        sm[t] += add;
        __syncthreads();
    }
    boff[t] = sm[t] - v;   // exclusive
}

// ---- phase 2: per-bucket histogram + scan + scatter; writes rp AND ssrc ----
__global__ __launch_bounds__(1024) void phase2_build(
    const uint* __restrict__ pairs, const int* __restrict__ pcur,
    const int* __restrict__ boff,
    int* __restrict__ rp, int* __restrict__ ssrc, int n)
{
    __shared__ int hist[512], cur[512];
    const int k = blockIdx.x;
    const int t = threadIdx.x;
    const int beg = k * BCAP;
    const int cnt = pcur[k] - beg;
    const int bbase = boff[k];
    const int dbase = k << 9;

    if (t < 512) hist[t] = 0;
    __syncthreads();

    uint pp[10];
    int m = 0;
    for (int i = t; i < cnt; i += 1024) {
        uint p = pairs[beg + i];
        pp[m++] = p;
        atomicAdd(&hist[p >> 17], 1);
    }
    __syncthreads();

    int c0 = (t < 512) ? hist[t] : 0;
    // inclusive scan over 512
    for (int off = 1; off < 512; off <<= 1) {
        int add = 0;
        if (t < 512 && t >= off) add = hist[t - off];
        __syncthreads();
        if (t < 512) hist[t] += add;
        __syncthreads();
    }
    if (t < 512) {
        int node = dbase + t;
        if (node < n) rp[node] = bbase + hist[t];   // end offset (global CSR)
        cur[t] = hist[t] - c0;                      // exclusive start (bucket-rel)
    }
    __syncthreads();

    m = 0;
    for (int i = t; i < cnt; i += 1024) {
        uint p = pp[m++];
        int j = p >> 17;
        int pos = bbase + atomicAdd(&cur[j], 1);
        ssrc[pos] = (int)(p & 0x1FFFF);
    }
}

// ---- pull-gather layer 1: wave per node, fused softmax-norm + bias + ELU ----
__global__ __launch_bounds__(256) void gather_h8(
    const int* __restrict__ rp, const int* __restrict__ ssrc,
    const float* __restrict__ a_src, const float* __restrict__ a_dst,
    const ushort* __restrict__ HB, const float* __restrict__ b,
    float* __restrict__ B, int n)
{
    int node = blockIdx.x * 4 + (threadIdx.x >> 6);
    if (node >= n) return;
    int lane = threadIdx.x & 63;
    int end = rp[node];
    int start = node ? rp[node - 1] : 0;
    int head = lane >> 3;
    float ad = a_dst[(size_t)node * 8 + head];
    float acc = 0.f, dsum = 0.f;

    for (int i0 = start; i0 < end; i0 += 64) {
        int cnt = min(64, end - i0);
        int sv = (i0 + lane < end) ? ssrc[i0 + lane] : 0;
        int j = 0;
        for (; j + 4 <= cnt; j += 4) {
            int s0 = __shfl(sv, j, 64);
            int s1 = __shfl(sv, j + 1, 64);
            int s2 = __shfl(sv, j + 2, 64);
            int s3 = __shfl(sv, j + 3, 64);
            float as0 = a_src[(size_t)s0 * 8 + head];
            float as1 = a_src[(size_t)s1 * 8 + head];
            float as2 = a_src[(size_t)s2 * 8 + head];
            float as3 = a_src[(size_t)s3 * 8 + head];
            float h0 = bf2f(HB[(size_t)s0 * 64 + lane]);
            float h1 = bf2f(HB[(size_t)s1 * 64 + lane]);
            float h2 = bf2f(HB[(size_t)s2 * 64 + lane]);
            float h3 = bf2f(HB[(size_t)s3 * 64 + lane]);
            float ex0 = __expf(lrelu(as0 + ad));
            float ex1 = __expf(lrelu(as1 + ad));
            float ex2 = __expf(lrelu(as2 + ad));
            float ex3 = __expf(lrelu(as3 + ad));
            dsum += (ex0 + ex1) + (ex2 + ex3);
            acc += ex0 * h0 + ex1 * h1 + ex2 * h2 + ex3 * h3;
        }
        for (; j < cnt; ++j) {
            int s0 = __shfl(sv, j, 64);
            float as0 = a_src[(size_t)s0 * 8 + head];
            float h0 = bf2f(HB[(size_t)s0 * 64 + lane]);
            float ex0 = __expf(lrelu(as0 + ad));
            dsum += ex0;
            acc += ex0 * h0;
        }
    }
    float v = acc / (dsum + 1e-16f) + b[lane];
    B[(size_t)node * 64 + lane] = v > 0.f ? v : expm1f(v);
}

// ---- pull-gather layer 2: wave per node, fused norm + bias + log_softmax ----
__global__ __launch_bounds__(256) void gather_h1_lsm(
    const int* __restrict__ rp, const int* __restrict__ ssrc,
    const float* __restrict__ a_src, const float* __restrict__ a_dst,
    const ushort* __restrict__ HB, const float* __restrict__ b,
    float* __restrict__ OUT, int n)
{
    int node = blockIdx.x * 4 + (threadIdx.x >> 6);
    if (node >= n) return;
    int lane = threadIdx.x & 63;
    int end = rp[node];
    int start = node ? rp[node - 1] : 0;
    float ad = a_dst[node];
    float acc = 0.f, dsum = 0.f;

    for (int i0 = start; i0 < end; i0 += 64) {
        int cnt = min(64, end - i0);
        int sv = (i0 + lane < end) ? ssrc[i0 + lane] : 0;
        int j = 0;
        for (; j + 4 <= cnt; j += 4) {
            int s0 = __shfl(sv, j, 64);
            int s1 = __shfl(sv, j + 1, 64);
            int s2 = __shfl(sv, j + 2, 64);
            int s3 = __shfl(sv, j + 3, 64);
            float as0 = a_src[s0];
            float as1 = a_src[s1];
            float as2 = a_src[s2];
            float as3 = a_src[s3];
            float h0 = bf2f(HB[(size_t)s0 * 64 + lane]);
            float h1 = bf2f(HB[(size_t)s1 * 64 + lane]);
            float h2 = bf2f(HB[(size_t)s2 * 64 + lane]);
            float h3 = bf2f(HB[(size_t)s3 * 64 + lane]);
            float ex0 = __expf(lrelu(as0 + ad));
            float ex1 = __expf(lrelu(as1 + ad));
            float ex2 = __expf(lrelu(as2 + ad));
            float ex3 = __expf(lrelu(as3 + ad));
            dsum += (ex0 + ex1) + (ex2 + ex3);
            acc += ex0 * h0 + ex1 * h1 + ex2 * h2 + ex3 * h3;
        }
        for (; j < cnt; ++j) {
            int s0 = __shfl(sv, j, 64);
            float as0 = a_src[s0];
            float h0 = bf2f(HB[(size_t)s0 * 64 + lane]);
            float ex0 = __expf(lrelu(as0 + ad));
            dsum += ex0;
            acc += ex0 * h0;
        }
    }
    float v = acc / (dsum + 1e-16f) + b[lane];
    float m = v;
    #pragma unroll
    for (int off = 1; off < 64; off <<= 1) m = fmaxf(m, __shfl_xor(m, off));
    float ex = __expf(v - m);
    float sum = ex;
    #pragma unroll
    for (int off = 1; off < 64; off <<= 1) sum += __shfl_xor(sum, off);
    OUT[(size_t)node * 64 + lane] = v - m - __logf(sum);
}

extern "C" void kernel_launch(void* const* d_in, const int* in_sizes, int n_in,
                              void* d_out, int out_size, void* d_ws, size_t ws_size,
                              hipStream_t stream)
{
    const float* x    = (const float*)d_in[0];
    const int*   ei   = (const int*)d_in[1];
    const float* W1   = (const float*)d_in[2];
    const float* as1w = (const float*)d_in[3];
    const float* ad1w = (const float*)d_in[4];
    const float* b1   = (const float*)d_in[5];
    const float* W2   = (const float*)d_in[6];
    const float* as2w = (const float*)d_in[7];
    const float* ad2w = (const float*)d_in[8];
    const float* b2   = (const float*)d_in[9];
    float* out = (float*)d_out;

    const int n  = in_sizes[0] / 256;     // 100000
    const int E_ = in_sizes[1] / 2;       // 1600000
    const int ET = E_ + n;
    const int NBUKU = (n + 511) >> 9;     // 196 used buckets

    char* wsb = (char*)d_ws;
    float*  B    = (float*)wsb;                          // [n*64] f32 (aliases pairs)
    uint*   pairs= (uint*)wsb;                           // [NBUK*BCAP] (build-time only)
    ushort* HB   = (ushort*)(B + (size_t)n * 64);        // [n*64] bf16
    float*  a_s1 = (float*)(HB + (size_t)n * 64);        // [n*8]
    float*  a_d1 = a_s1 + (size_t)n * 8;                 // [n*8]
    float*  a_s2 = a_d1 + (size_t)n * 8;                 // [n]
    float*  a_d2 = a_s2 + n;                             // [n]
    int*    rp   = (int*)(a_d2 + n);                     // [n]
    int*    pcur = rp + n;                               // [NBUK]
    int*    boff = pcur + NBUK;                          // [NBUK]
    int*    ssrc = boff + NBUK;                          // [ET]

    const int gemm_grid = (n + 63) / 64;
    const int node_grid = (n + 3) / 4;
    const int part_grid = (ET + CH2 - 1) / CH2;

    // ---- CSR build (reused by both layers) ----
    init_pcur<<<1, NBUK, 0, stream>>>(pcur);
    partition_pairs<<<part_grid, 1024, 0, stream>>>(ei, E_, ET, pcur, pairs);
    bucket_scan<<<1, NBUK, 0, stream>>>(pcur, boff, NBUKU);
    phase2_build<<<NBUKU, 1024, 0, stream>>>(pairs, pcur, boff, rp, ssrc, n);

    // ---- layer 1 ----
    gemm_bf16out<256><<<gemm_grid, 256, 0, stream>>>(x, W1, HB, n);
    node_att_h8<<<node_grid, 256, 0, stream>>>(HB, as1w, ad1w, a_s1, a_d1, n);
    gather_h8<<<node_grid, 256, 0, stream>>>(rp, ssrc, a_s1, a_d1, HB, b1, B, n);

    // ---- layer 2 ----
    gemm_bf16out<64><<<gemm_grid, 256, 0, stream>>>(B, W2, HB, n);
    node_att_h1<<<node_grid, 256, 0, stream>>>(HB, as2w, ad2w, a_s2, a_d2, n);
    gather_h1_lsm<<<node_grid, 256, 0, stream>>>(rp, ssrc, a_s2, a_d2, HB, b2, out, n);
}